// Round 2
// baseline (428.643 us; speedup 1.0000x reference)
//
#include <hip/hip_runtime.h>

// ChessboardLayer: space-to-depth into 8x8 cell grid.
// Input  (B=32, H=256, W=256, C=32) fp32, NHWC contiguous.
// Output (B, 8, 8, 32768) fp32.
//
// The op is a permutation of 65536 contiguous 4 KiB blocks:
//   out block: blk    = ((b*8 + i)*8 + j)*32 + r
//   in  block: in_blk = (b*256 + i*32 + r)*8 + j
//
// R1 change: 16 blocks per workgroup, 16 independent float4 copies per
// thread (load-all-then-store-all) to amortize wave preamble and expose
// memory-level parallelism. R0's one-load-one-store-per-wave version was
// latency-bound at 1.26 TB/s.

__global__ __launch_bounds__(256) void chessboard_kernel(
    const float4* __restrict__ in, float4* __restrict__ out) {
    const unsigned tid      = threadIdx.x;
    const unsigned base_blk = blockIdx.x * 16u;   // first output 4KiB block

    float4 v[16];
#pragma unroll
    for (int k = 0; k < 16; ++k) {
        unsigned blk = base_blk + (unsigned)k;
        unsigned r = blk & 31u;
        unsigned j = (blk >> 5) & 7u;
        unsigned i = (blk >> 8) & 7u;
        unsigned b = blk >> 11;
        unsigned in_blk = (b * 256u + i * 32u + r) * 8u + j;
        v[k] = in[in_blk * 256u + tid];
    }
#pragma unroll
    for (int k = 0; k < 16; ++k) {
        out[(base_blk + (unsigned)k) * 256u + tid] = v[k];
    }
}

extern "C" void kernel_launch(void* const* d_in, const int* in_sizes, int n_in,
                              void* d_out, int out_size, void* d_ws, size_t ws_size,
                              hipStream_t stream) {
    const float4* in  = (const float4*)d_in[0];
    float4*       out = (float4*)d_out;
    // 65536 output blocks / 16 per workgroup = 4096 workgroups
    chessboard_kernel<<<4096, 256, 0, stream>>>(in, out);
}